// Round 16
// baseline (148.038 us; speedup 1.0000x reference)
//
#include <hip/hip_runtime.h>

#define NODES 100000
#define EDGES 640000
#define DF 128
#define SLOT 24                 // 96B/node bucket; Poisson(6.4) P(deg>24) ~ 1.5e-8 -> zero overflow on this input
#define OVF_CAP 4096
#define MBLK 1563               // (NODES+63)/64 gemm blocks

typedef short bf16x8 __attribute__((ext_vector_type(8)));
typedef float f32x4 __attribute__((ext_vector_type(4)));

__device__ __forceinline__ unsigned short f2bf(float f) {
    unsigned u = __builtin_bit_cast(unsigned, f);
    u += 0x7FFFu + ((u >> 16) & 1u);          // round-to-nearest-even
    return (unsigned short)(u >> 16);
}
__device__ __forceinline__ float bflo(unsigned w) { return __builtin_bit_cast(float, w << 16); }
__device__ __forceinline__ float bfhi(unsigned w) { return __builtin_bit_cast(float, w & 0xFFFF0000u); }

// ---------------------------------------------------------------- prep: W transpose->bf16, zero cursor/ovf
__global__ void prep_all(const float* __restrict__ W1, const float* __restrict__ W2,
                         unsigned short* __restrict__ Wt1, unsigned short* __restrict__ Wt2,
                         uint4* __restrict__ cursor4, int* __restrict__ ovf) {
    const int idx = blockIdx.x * blockDim.x + threadIdx.x;
    if (idx < 32768) {
        const float* src = (idx < 16384) ? W1 : W2;
        unsigned short* dst = (idx < 16384) ? Wt1 : Wt2;
        const int r = idx & 16383;
        const int n = r & 127, k = r >> 7;
        dst[n * 128 + k] = f2bf(src[k * 128 + n]);
    } else {
        const int z = idx - 32768;
        if (z < NODES / 4) cursor4[z] = make_uint4(0u, 0u, 0u, 0u);
        else if (z == NODES / 4) ovf[0] = 0;
    }
}

// ---------------------------------------------------------------- bucket fill (1 edge/thread; 640K threads = TLP-saturated;
// ~45us is the empirical floor for 640K random-line atomic-RMW+scatter — bracketed by rounds 11/13/14/15)
__global__ void fill_bucket(const int* __restrict__ srcIdx,
                            const int* __restrict__ dstIdx,
                            int* __restrict__ cursor,
                            int* __restrict__ slots,
                            int* __restrict__ ovf) {
    const int e = blockIdx.x * blockDim.x + threadIdx.x;
    if (e < EDGES) {
        const int d = dstIdx[e];
        const int s = srcIdx[e];
        const int pos = atomicAdd(&cursor[d], 1);
        if (pos < SLOT) {
            slots[d * SLOT + pos] = s;
        } else {
            const int k = atomicAdd(&ovf[0], 1);
            if (k < OVF_CAP) { ovf[1 + 2 * k] = d; ovf[2 + 2 * k] = s; }
        }
    }
}

// ---------------------------------------------------------------- GEMM: Y = A @ Wt^T (bf16 out)
template <int A_F32>
__global__ __launch_bounds__(256) void gemm_mfma(const void* __restrict__ Ap,
                                                 const uint4* __restrict__ Wt4,
                                                 unsigned short* __restrict__ outh) {
    __shared__ __align__(16) unsigned char wlds[32768];
    __shared__ __align__(16) unsigned char epi[16384];

    const int tid = threadIdx.x;
    #pragma unroll
    for (int i = 0; i < 8; ++i) {
        const int c = i * 256 + tid;
        const uint4 v = Wt4[c];
        const int byte = (c * 16) ^ (((c >> 4) & 7) << 4);
        *(uint4*)(wlds + byte) = v;
    }

    const int wv = tid >> 6;
    const int l  = tid & 63;
    const int lr = l & 15;
    const int g  = l >> 4;
    const int row0 = blockIdx.x * 64 + wv * 16;

    int arow = row0 + lr;
    if (arow >= NODES) arow = 0;      // clamp (stores guarded)

    bf16x8 af[4];
    if constexpr (A_F32) {
        const float* Af = (const float*)Ap + (size_t)arow * DF + g * 8;
        #pragma unroll
        for (int t = 0; t < 4; ++t) {
            const float4 f0 = *(const float4*)(Af + t * 32);
            const float4 f1 = *(const float4*)(Af + t * 32 + 4);
            bf16x8 v;
            v[0] = (short)f2bf(f0.x); v[1] = (short)f2bf(f0.y);
            v[2] = (short)f2bf(f0.z); v[3] = (short)f2bf(f0.w);
            v[4] = (short)f2bf(f1.x); v[5] = (short)f2bf(f1.y);
            v[6] = (short)f2bf(f1.z); v[7] = (short)f2bf(f1.w);
            af[t] = v;
        }
    } else {
        const unsigned short* Ab = (const unsigned short*)Ap + (size_t)arow * DF + g * 8;
        #pragma unroll
        for (int t = 0; t < 4; ++t) af[t] = *(const bf16x8*)(Ab + t * 32);
    }

    f32x4 acc[8];
    #pragma unroll
    for (int nt = 0; nt < 8; ++nt) acc[nt] = (f32x4)(0.f);

    __syncthreads();

    #pragma unroll
    for (int t = 0; t < 4; ++t) {
        #pragma unroll
        for (int nt = 0; nt < 8; ++nt) {
            const int byte = ((nt * 16 + lr) * 256 + ((((t * 4 + g) * 16) ^ ((l & 7) << 4))));
            const bf16x8 bf = *(const bf16x8*)(wlds + byte);
            acc[nt] = __builtin_amdgcn_mfma_f32_16x16x32_bf16(af[t], bf, acc[nt], 0, 0, 0);
        }
    }

    // epilogue: transpose via per-wave LDS for coalesced bf16 row stores
    unsigned char* my = epi + wv * 4096;
    #pragma unroll
    for (int nt = 0; nt < 8; ++nt) {
        #pragma unroll
        for (int r = 0; r < 4; ++r) {
            const int R = g * 4 + r;
            const int byte = (R * 256 + (nt * 16 + lr) * 2) ^ ((R & 7) << 4);
            *(unsigned short*)(my + byte) = f2bf(acc[nt][r]);
        }
    }
    __syncthreads();
    #pragma unroll
    for (int p = 0; p < 4; ++p) {
        const int R = p * 4 + g;
        const uint4 v = *(const uint4*)(my + ((R * 256 + lr * 16) ^ ((R & 7) << 4)));
        const int gr = row0 + R;
        if (gr < NODES) *(uint4*)(outh + (size_t)gr * DF + lr * 8) = v;
    }
}

// ---------------------------------------------------------------- gather+bias(+relu): out[i] = y[i] + sum_N y[j] + b
template <int RELU, int OUT_F32>
__global__ __launch_bounds__(256) void gather_bias(const uint4* __restrict__ yb,
                                                   const int* __restrict__ cursor,
                                                   const int* __restrict__ slots,
                                                   const int* __restrict__ ovf,
                                                   const float* __restrict__ bias,
                                                   void* __restrict__ outp) {
    const int gid = blockIdx.x * 256 + threadIdx.x;
    const int node = gid >> 4;
    const int lane = gid & 15;
    if (node >= NODES) return;

    float a[8];
    {
        const uint4 u = yb[(size_t)node * 16 + lane];
        a[0] = bflo(u.x); a[1] = bfhi(u.x);
        a[2] = bflo(u.y); a[3] = bfhi(u.y);
        a[4] = bflo(u.z); a[5] = bfhi(u.z);
        a[6] = bflo(u.w); a[7] = bfhi(u.w);
    }
    const int deg = min(cursor[node], SLOT);
    const int base = node * SLOT;
    int j = 0;
    for (; j + 4 <= deg; j += 4) {
        const int s0 = slots[base + j + 0];
        const int s1 = slots[base + j + 1];
        const int s2 = slots[base + j + 2];
        const int s3 = slots[base + j + 3];
        const uint4 v0 = yb[(size_t)s0 * 16 + lane];
        const uint4 v1 = yb[(size_t)s1 * 16 + lane];
        const uint4 v2 = yb[(size_t)s2 * 16 + lane];
        const uint4 v3 = yb[(size_t)s3 * 16 + lane];
        a[0] += bflo(v0.x); a[1] += bfhi(v0.x); a[2] += bflo(v0.y); a[3] += bfhi(v0.y);
        a[4] += bflo(v0.z); a[5] += bfhi(v0.z); a[6] += bflo(v0.w); a[7] += bfhi(v0.w);
        a[0] += bflo(v1.x); a[1] += bfhi(v1.x); a[2] += bflo(v1.y); a[3] += bfhi(v1.y);
        a[4] += bflo(v1.z); a[5] += bfhi(v1.z); a[6] += bflo(v1.w); a[7] += bfhi(v1.w);
        a[0] += bflo(v2.x); a[1] += bfhi(v2.x); a[2] += bflo(v2.y); a[3] += bfhi(v2.y);
        a[4] += bflo(v2.z); a[5] += bfhi(v2.z); a[6] += bflo(v2.w); a[7] += bfhi(v2.w);
        a[0] += bflo(v3.x); a[1] += bfhi(v3.x); a[2] += bflo(v3.y); a[3] += bfhi(v3.y);
        a[4] += bflo(v3.z); a[5] += bfhi(v3.z); a[6] += bflo(v3.w); a[7] += bfhi(v3.w);
    }
    for (; j < deg; ++j) {
        const uint4 v = yb[(size_t)slots[base + j] * 16 + lane];
        a[0] += bflo(v.x); a[1] += bfhi(v.x); a[2] += bflo(v.y); a[3] += bfhi(v.y);
        a[4] += bflo(v.z); a[5] += bfhi(v.z); a[6] += bflo(v.w); a[7] += bfhi(v.w);
    }

    // overflow edges (count 0 on this input; one cached uniform read)
    const int oc = ovf[0];
    if (oc > 0) {
        const int m = min(oc, OVF_CAP);
        for (int k = 0; k < m; ++k) {
            if (ovf[1 + 2 * k] == node) {
                const uint4 v = yb[(size_t)ovf[2 + 2 * k] * 16 + lane];
                a[0] += bflo(v.x); a[1] += bfhi(v.x); a[2] += bflo(v.y); a[3] += bfhi(v.y);
                a[4] += bflo(v.z); a[5] += bfhi(v.z); a[6] += bflo(v.w); a[7] += bfhi(v.w);
            }
        }
    }

    const float4 bb0 = ((const float4*)bias)[lane * 2 + 0];
    const float4 bb1 = ((const float4*)bias)[lane * 2 + 1];
    a[0] += bb0.x; a[1] += bb0.y; a[2] += bb0.z; a[3] += bb0.w;
    a[4] += bb1.x; a[5] += bb1.y; a[6] += bb1.z; a[7] += bb1.w;
    if (RELU) {
        #pragma unroll
        for (int e = 0; e < 8; ++e) a[e] = fmaxf(a[e], 0.f);
    }

    if constexpr (OUT_F32) {
        float* of = (float*)outp + (size_t)node * DF + lane * 8;
        *(float4*)(of + 0) = make_float4(a[0], a[1], a[2], a[3]);
        *(float4*)(of + 4) = make_float4(a[4], a[5], a[6], a[7]);
    } else {
        uint4 o;
        o.x = (unsigned)f2bf(a[0]) | ((unsigned)f2bf(a[1]) << 16);
        o.y = (unsigned)f2bf(a[2]) | ((unsigned)f2bf(a[3]) << 16);
        o.z = (unsigned)f2bf(a[4]) | ((unsigned)f2bf(a[5]) << 16);
        o.w = (unsigned)f2bf(a[6]) | ((unsigned)f2bf(a[7]) << 16);
        ((uint4*)outp)[(size_t)node * 16 + lane] = o;
    }
}

extern "C" void kernel_launch(void* const* d_in, const int* in_sizes, int n_in,
                              void* d_out, int out_size, void* d_ws, size_t ws_size,
                              hipStream_t stream) {
    const float* x  = (const float*)d_in[0];
    const int*   ei = (const int*)d_in[1];
    const float* W1 = (const float*)d_in[2];
    const float* b1 = (const float*)d_in[3];
    const float* W2 = (const float*)d_in[4];
    const float* b2 = (const float*)d_in[5];
    float* out = (float*)d_out;

    const int* src = ei;
    const int* dst = ei + EDGES;

    // workspace layout
    unsigned short* B0  = (unsigned short*)d_ws;                  // NODES*DF bf16 (y / z)
    unsigned short* B1  = B0 + (size_t)NODES * DF;                // NODES*DF bf16 (h)
    unsigned short* Wt1 = B1 + (size_t)NODES * DF;                // 16384
    unsigned short* Wt2 = Wt1 + 16384;                            // 16384
    int* cursor = (int*)(Wt2 + 16384);                            // NODES
    int* slots  = cursor + NODES;                                 // NODES*SLOT (9.6 MB)
    int* ovf    = slots + (size_t)NODES * SLOT;                   // 1 + 2*OVF_CAP

    // 1: W transpose + zero cursor/ovf
    prep_all<<<(32768 + NODES / 4 + 1 + 255) / 256, 256, 0, stream>>>(W1, W2, Wt1, Wt2,
                                                                      (uint4*)cursor, ovf);
    // 2: bucket fill
    fill_bucket<<<(EDGES + 255) / 256, 256, 0, stream>>>(src, dst, cursor, slots, ovf);

    const int gblocks = (NODES * 16 + 255) / 256;   // 6250

    // 3: y = x @ W1
    gemm_mfma<1><<<MBLK, 256, 0, stream>>>((const void*)x, (const uint4*)Wt1, B0);
    // 4: h = relu(y_i + sum_N y_j + b1)
    gather_bias<1, 0><<<gblocks, 256, 0, stream>>>((const uint4*)B0, cursor, slots, ovf, b1, B1);
    // 5: z = h @ W2
    gemm_mfma<0><<<MBLK, 256, 0, stream>>>((const void*)B1, (const uint4*)Wt2, B0);
    // 6: out = z_i + sum_N z_j + b2
    gather_bias<0, 1><<<gblocks, 256, 0, stream>>>((const uint4*)B0, cursor, slots, ovf, b2, out);
}

// Round 17
// 140.338 us; speedup vs baseline: 1.0549x; 1.0549x over previous
//
#include <hip/hip_runtime.h>

#define NODES 100000
#define EDGES 640000
#define DF 128
#define SLOT 24                 // per-node slots; Poisson(6.4) P(>24) ~ 1e-8
#define OVF_CAP 4096
#define MBLK 1563               // (NODES+63)/64 gemm blocks

#define BINS 100                // nodes 0..99999 -> bin = d/1000
#define NPB 1000                // nodes per bin
#define CAP1 96                 // LDS bin cap (pass 1); mean 40/block
#define GCAP 8000               // global bin cap; mean 6400
#define CHUNK 4000              // edges per pass-1 block
#define P1BLK 160               // 160*4000 = 640000

typedef short bf16x8 __attribute__((ext_vector_type(8)));
typedef float f32x4 __attribute__((ext_vector_type(4)));

__device__ __forceinline__ unsigned short f2bf(float f) {
    unsigned u = __builtin_bit_cast(unsigned, f);
    u += 0x7FFFu + ((u >> 16) & 1u);          // round-to-nearest-even
    return (unsigned short)(u >> 16);
}
__device__ __forceinline__ float bflo(unsigned w) { return __builtin_bit_cast(float, w << 16); }
__device__ __forceinline__ float bfhi(unsigned w) { return __builtin_bit_cast(float, w & 0xFFFF0000u); }

// ---------------------------------------------------------------- prep: W transpose->bf16, zero gcnt/ovf
__global__ void prep_all(const float* __restrict__ W1, const float* __restrict__ W2,
                         unsigned short* __restrict__ Wt1, unsigned short* __restrict__ Wt2,
                         int* __restrict__ gcnt, int* __restrict__ ovf) {
    const int idx = blockIdx.x * blockDim.x + threadIdx.x;
    if (idx < 32768) {
        const float* src = (idx < 16384) ? W1 : W2;
        unsigned short* dst = (idx < 16384) ? Wt1 : Wt2;
        const int r = idx & 16383;
        const int n = r & 127, k = r >> 7;
        dst[n * 128 + k] = f2bf(src[k * 128 + n]);
    } else {
        const int z = idx - 32768;
        if (z < BINS) gcnt[z] = 0;
        else if (z == BINS) ovf[0] = 0;
    }
}

// ---------------------------------------------------------------- pass 1: LDS-binned scatter -> dense global bin segments
__global__ __launch_bounds__(256) void bin_scatter(const int* __restrict__ srcIdx,
                                                   const int* __restrict__ dstIdx,
                                                   int* __restrict__ gcnt,
                                                   int2* __restrict__ gbin,
                                                   int* __restrict__ ovf) {
    __shared__ int2 lsbin[BINS * CAP1];   // 76.8 KB
    __shared__ int lcnt[BINS];
    __shared__ int lbase[BINS];
    __shared__ int pref[BINS + 1];

    const int tid = threadIdx.x;
    for (int i = tid; i < BINS; i += 256) lcnt[i] = 0;
    __syncthreads();

    const int e0 = blockIdx.x * CHUNK;
    for (int i = tid; i < CHUNK; i += 256) {
        const int e = e0 + i;
        const int d = dstIdx[e];
        const int s = srcIdx[e];
        const int b = d / NPB;
        const int pos = atomicAdd(&lcnt[b], 1);
        if (pos < CAP1) {
            lsbin[b * CAP1 + pos] = make_int2(s, d);
        } else {
            const int k = atomicAdd(&ovf[0], 1);
            if (k < OVF_CAP) { ovf[1 + 2 * k] = d; ovf[2 + 2 * k] = s; }
        }
    }
    __syncthreads();

    // clamp counts, reserve global segment space (one atomic per bin per block)
    if (tid < BINS) {
        const int c = min(lcnt[tid], CAP1);
        lcnt[tid] = c;
        lbase[tid] = atomicAdd(&gcnt[tid], c);
    }
    __syncthreads();
    if (tid == 0) {
        int acc = 0;
        for (int b = 0; b < BINS; ++b) { pref[b] = acc; acc += lcnt[b]; }
        pref[BINS] = acc;
    }
    __syncthreads();

    // dense coalesced copy-out: flat index -> (bin, j) via binary search on prefix
    const int total = pref[BINS];
    for (int f = tid; f < total; f += 256) {
        int lo = 0, hi = BINS - 1;
        while (lo < hi) { const int mid = (lo + hi + 1) >> 1; if (pref[mid] <= f) lo = mid; else hi = mid - 1; }
        const int j = f - pref[lo];
        const int gi = lbase[lo] + j;
        const int2 ed = lsbin[lo * CAP1 + j];
        if (gi < GCAP) {
            gbin[(size_t)lo * GCAP + gi] = ed;
        } else {
            const int k = atomicAdd(&ovf[0], 1);
            if (k < OVF_CAP) { ovf[1 + 2 * k] = ed.y; ovf[2 + 2 * k] = ed.x; }
        }
    }
}

// ---------------------------------------------------------------- pass 2: per-bin LDS build -> dense cursor/slots
__global__ __launch_bounds__(256) void bin_build(const int* __restrict__ gcnt,
                                                 const int2* __restrict__ gbin,
                                                 int* __restrict__ cursor,
                                                 int* __restrict__ slots,
                                                 int* __restrict__ ovf) {
    __shared__ int lcur[NPB];             // 4 KB
    __shared__ int lslot[NPB * SLOT];     // 96 KB
    const int b = blockIdx.x;
    const int tid = threadIdx.x;
    for (int i = tid; i < NPB; i += 256) lcur[i] = 0;
    __syncthreads();

    const int cnt = min(gcnt[b], GCAP);
    for (int i = tid; i < cnt; i += 256) {
        const int2 ed = gbin[(size_t)b * GCAP + i];
        const int ln = ed.y - b * NPB;
        const int pos = atomicAdd(&lcur[ln], 1);
        if (pos < SLOT) {
            lslot[ln * SLOT + pos] = ed.x;
        } else {
            const int k = atomicAdd(&ovf[0], 1);
            if (k < OVF_CAP) { ovf[1 + 2 * k] = ed.y; ovf[2 + 2 * k] = ed.x; }
        }
    }
    __syncthreads();

    for (int i = tid; i < NPB; i += 256) cursor[b * NPB + i] = lcur[i];
    for (int i = tid; i < NPB * SLOT; i += 256)
        slots[(size_t)b * NPB * SLOT + i] = lslot[i];   // == slots[node*SLOT + j], dense
}

// ---------------------------------------------------------------- GEMM: Y = A @ Wt^T (bf16 out)
template <int A_F32>
__global__ __launch_bounds__(256) void gemm_mfma(const void* __restrict__ Ap,
                                                 const uint4* __restrict__ Wt4,
                                                 unsigned short* __restrict__ outh) {
    __shared__ __align__(16) unsigned char wlds[32768];
    __shared__ __align__(16) unsigned char epi[16384];

    const int tid = threadIdx.x;
    #pragma unroll
    for (int i = 0; i < 8; ++i) {
        const int c = i * 256 + tid;
        const uint4 v = Wt4[c];
        const int byte = (c * 16) ^ (((c >> 4) & 7) << 4);
        *(uint4*)(wlds + byte) = v;
    }

    const int wv = tid >> 6;
    const int l  = tid & 63;
    const int lr = l & 15;
    const int g  = l >> 4;
    const int row0 = blockIdx.x * 64 + wv * 16;

    int arow = row0 + lr;
    if (arow >= NODES) arow = 0;      // clamp (stores guarded)

    bf16x8 af[4];
    if constexpr (A_F32) {
        const float* Af = (const float*)Ap + (size_t)arow * DF + g * 8;
        #pragma unroll
        for (int t = 0; t < 4; ++t) {
            const float4 f0 = *(const float4*)(Af + t * 32);
            const float4 f1 = *(const float4*)(Af + t * 32 + 4);
            bf16x8 v;
            v[0] = (short)f2bf(f0.x); v[1] = (short)f2bf(f0.y);
            v[2] = (short)f2bf(f0.z); v[3] = (short)f2bf(f0.w);
            v[4] = (short)f2bf(f1.x); v[5] = (short)f2bf(f1.y);
            v[6] = (short)f2bf(f1.z); v[7] = (short)f2bf(f1.w);
            af[t] = v;
        }
    } else {
        const unsigned short* Ab = (const unsigned short*)Ap + (size_t)arow * DF + g * 8;
        #pragma unroll
        for (int t = 0; t < 4; ++t) af[t] = *(const bf16x8*)(Ab + t * 32);
    }

    f32x4 acc[8];
    #pragma unroll
    for (int nt = 0; nt < 8; ++nt) acc[nt] = (f32x4)(0.f);

    __syncthreads();

    #pragma unroll
    for (int t = 0; t < 4; ++t) {
        #pragma unroll
        for (int nt = 0; nt < 8; ++nt) {
            const int byte = ((nt * 16 + lr) * 256 + ((((t * 4 + g) * 16) ^ ((l & 7) << 4))));
            const bf16x8 bf = *(const bf16x8*)(wlds + byte);
            acc[nt] = __builtin_amdgcn_mfma_f32_16x16x32_bf16(af[t], bf, acc[nt], 0, 0, 0);
        }
    }

    // epilogue: transpose via per-wave LDS for coalesced bf16 row stores
    unsigned char* my = epi + wv * 4096;
    #pragma unroll
    for (int nt = 0; nt < 8; ++nt) {
        #pragma unroll
        for (int r = 0; r < 4; ++r) {
            const int R = g * 4 + r;
            const int byte = (R * 256 + (nt * 16 + lr) * 2) ^ ((R & 7) << 4);
            *(unsigned short*)(my + byte) = f2bf(acc[nt][r]);
        }
    }
    __syncthreads();
    #pragma unroll
    for (int p = 0; p < 4; ++p) {
        const int R = p * 4 + g;
        const uint4 v = *(const uint4*)(my + ((R * 256 + lr * 16) ^ ((R & 7) << 4)));
        const int gr = row0 + R;
        if (gr < NODES) *(uint4*)(outh + (size_t)gr * DF + lr * 8) = v;
    }
}

// ---------------------------------------------------------------- gather+bias(+relu): out[i] = y[i] + sum_N y[j] + b
template <int RELU, int OUT_F32>
__global__ __launch_bounds__(256) void gather_bias(const uint4* __restrict__ yb,
                                                   const int* __restrict__ cursor,
                                                   const int* __restrict__ slots,
                                                   const int* __restrict__ ovf,
                                                   const float* __restrict__ bias,
                                                   void* __restrict__ outp) {
    const int gid = blockIdx.x * 256 + threadIdx.x;
    const int node = gid >> 4;
    const int lane = gid & 15;
    if (node >= NODES) return;

    float a[8];
    {
        const uint4 u = yb[(size_t)node * 16 + lane];
        a[0] = bflo(u.x); a[1] = bfhi(u.x);
        a[2] = bflo(u.y); a[3] = bfhi(u.y);
        a[4] = bflo(u.z); a[5] = bfhi(u.z);
        a[6] = bflo(u.w); a[7] = bfhi(u.w);
    }
    const int deg = min(cursor[node], SLOT);
    const int base = node * SLOT;
    int j = 0;
    for (; j + 4 <= deg; j += 4) {
        const int s0 = slots[base + j + 0];
        const int s1 = slots[base + j + 1];
        const int s2 = slots[base + j + 2];
        const int s3 = slots[base + j + 3];
        const uint4 v0 = yb[(size_t)s0 * 16 + lane];
        const uint4 v1 = yb[(size_t)s1 * 16 + lane];
        const uint4 v2 = yb[(size_t)s2 * 16 + lane];
        const uint4 v3 = yb[(size_t)s3 * 16 + lane];
        a[0] += bflo(v0.x); a[1] += bfhi(v0.x); a[2] += bflo(v0.y); a[3] += bfhi(v0.y);
        a[4] += bflo(v0.z); a[5] += bfhi(v0.z); a[6] += bflo(v0.w); a[7] += bfhi(v0.w);
        a[0] += bflo(v1.x); a[1] += bfhi(v1.x); a[2] += bflo(v1.y); a[3] += bfhi(v1.y);
        a[4] += bflo(v1.z); a[5] += bfhi(v1.z); a[6] += bflo(v1.w); a[7] += bfhi(v1.w);
        a[0] += bflo(v2.x); a[1] += bfhi(v2.x); a[2] += bflo(v2.y); a[3] += bfhi(v2.y);
        a[4] += bflo(v2.z); a[5] += bfhi(v2.z); a[6] += bflo(v2.w); a[7] += bfhi(v2.w);
        a[0] += bflo(v3.x); a[1] += bfhi(v3.x); a[2] += bflo(v3.y); a[3] += bfhi(v3.y);
        a[4] += bflo(v3.z); a[5] += bfhi(v3.z); a[6] += bflo(v3.w); a[7] += bfhi(v3.w);
    }
    for (; j < deg; ++j) {
        const uint4 v = yb[(size_t)slots[base + j] * 16 + lane];
        a[0] += bflo(v.x); a[1] += bfhi(v.x); a[2] += bflo(v.y); a[3] += bfhi(v.y);
        a[4] += bflo(v.z); a[5] += bfhi(v.z); a[6] += bflo(v.w); a[7] += bfhi(v.w);
    }

    // overflow edges (count 0 on this input; one cached uniform read)
    const int oc = ovf[0];
    if (oc > 0) {
        const int m = min(oc, OVF_CAP);
        for (int k = 0; k < m; ++k) {
            if (ovf[1 + 2 * k] == node) {
                const uint4 v = yb[(size_t)ovf[2 + 2 * k] * 16 + lane];
                a[0] += bflo(v.x); a[1] += bfhi(v.x); a[2] += bflo(v.y); a[3] += bfhi(v.y);
                a[4] += bflo(v.z); a[5] += bfhi(v.z); a[6] += bflo(v.w); a[7] += bfhi(v.w);
            }
        }
    }

    const float4 bb0 = ((const float4*)bias)[lane * 2 + 0];
    const float4 bb1 = ((const float4*)bias)[lane * 2 + 1];
    a[0] += bb0.x; a[1] += bb0.y; a[2] += bb0.z; a[3] += bb0.w;
    a[4] += bb1.x; a[5] += bb1.y; a[6] += bb1.z; a[7] += bb1.w;
    if (RELU) {
        #pragma unroll
        for (int e = 0; e < 8; ++e) a[e] = fmaxf(a[e], 0.f);
    }

    if constexpr (OUT_F32) {
        float* of = (float*)outp + (size_t)node * DF + lane * 8;
        *(float4*)(of + 0) = make_float4(a[0], a[1], a[2], a[3]);
        *(float4*)(of + 4) = make_float4(a[4], a[5], a[6], a[7]);
    } else {
        uint4 o;
        o.x = (unsigned)f2bf(a[0]) | ((unsigned)f2bf(a[1]) << 16);
        o.y = (unsigned)f2bf(a[2]) | ((unsigned)f2bf(a[3]) << 16);
        o.z = (unsigned)f2bf(a[4]) | ((unsigned)f2bf(a[5]) << 16);
        o.w = (unsigned)f2bf(a[6]) | ((unsigned)f2bf(a[7]) << 16);
        ((uint4*)outp)[(size_t)node * 16 + lane] = o;
    }
}

extern "C" void kernel_launch(void* const* d_in, const int* in_sizes, int n_in,
                              void* d_out, int out_size, void* d_ws, size_t ws_size,
                              hipStream_t stream) {
    const float* x  = (const float*)d_in[0];
    const int*   ei = (const int*)d_in[1];
    const float* W1 = (const float*)d_in[2];
    const float* b1 = (const float*)d_in[3];
    const float* W2 = (const float*)d_in[4];
    const float* b2 = (const float*)d_in[5];
    float* out = (float*)d_out;

    const int* src = ei;
    const int* dst = ei + EDGES;

    // workspace layout
    unsigned short* B0  = (unsigned short*)d_ws;                  // NODES*DF bf16 (y / z)
    unsigned short* B1  = B0 + (size_t)NODES * DF;                // NODES*DF bf16 (h)
    unsigned short* Wt1 = B1 + (size_t)NODES * DF;                // 16384
    unsigned short* Wt2 = Wt1 + 16384;                            // 16384
    int* cursor = (int*)(Wt2 + 16384);                            // NODES (fully written by bin_build)
    int* slots  = cursor + NODES;                                 // NODES*SLOT (9.6 MB)
    int* gcnt   = slots + (size_t)NODES * SLOT;                   // BINS
    int* ovf    = gcnt + BINS;                                    // 1 + 2*OVF_CAP
    int2* gbin  = (int2*)(((size_t)(ovf + 1 + 2 * OVF_CAP) + 15) & ~(size_t)15);  // BINS*GCAP int2 (6.4 MB)

    // 1: W transpose + zero gcnt/ovf
    prep_all<<<(32768 + BINS + 1 + 255) / 256, 256, 0, stream>>>(W1, W2, Wt1, Wt2, gcnt, ovf);
    // 2: pass 1 — LDS-binned scatter to dense bin segments
    bin_scatter<<<P1BLK, 256, 0, stream>>>(src, dst, gcnt, gbin, ovf);
    // 3: pass 2 — per-bin LDS build -> dense cursor/slots
    bin_build<<<BINS, 256, 0, stream>>>(gcnt, gbin, cursor, slots, ovf);

    const int gblocks = (NODES * 16 + 255) / 256;   // 6250

    // 4: y = x @ W1
    gemm_mfma<1><<<MBLK, 256, 0, stream>>>((const void*)x, (const uint4*)Wt1, B0);
    // 5: h = relu(y_i + sum_N y_j + b1)
    gather_bias<1, 0><<<gblocks, 256, 0, stream>>>((const uint4*)B0, cursor, slots, ovf, b1, B1);
    // 6: z = h @ W2
    gemm_mfma<0><<<MBLK, 256, 0, stream>>>((const void*)B1, (const uint4*)Wt2, B0);
    // 7: out = z_i + sum_N z_j + b2
    gather_bias<0, 1><<<gblocks, 256, 0, stream>>>((const uint4*)B0, cursor, slots, ovf, b2, out);
}

// Round 18
// 132.968 us; speedup vs baseline: 1.1133x; 1.0554x over previous
//
#include <hip/hip_runtime.h>

#define NODES 100000
#define EDGES 640000
#define DF 128
#define SLOT 24                 // per-node slots; Poisson(6.4) P(>24) ~ 1e-8
#define OVF_CAP 4096
#define MBLK 1563               // (NODES+63)/64 gemm blocks

#define BINS 200                // bin = d/500
#define NPB 500                 // nodes per bin
#define CAP1 40                 // LDS cell cap (pass 1); mean 12.5, P(>40)~5e-9
#define GCAP 4000               // global bin cap; mean 3200 (+14 sigma)
#define CHUNK 2500              // edges per pass-1 block
#define P1BLK 256               // 256*2500 = 640000

typedef short bf16x8 __attribute__((ext_vector_type(8)));
typedef float f32x4 __attribute__((ext_vector_type(4)));

__device__ __forceinline__ unsigned short f2bf(float f) {
    unsigned u = __builtin_bit_cast(unsigned, f);
    u += 0x7FFFu + ((u >> 16) & 1u);          // round-to-nearest-even
    return (unsigned short)(u >> 16);
}
__device__ __forceinline__ float bflo(unsigned w) { return __builtin_bit_cast(float, w << 16); }
__device__ __forceinline__ float bfhi(unsigned w) { return __builtin_bit_cast(float, w & 0xFFFF0000u); }

// ---------------------------------------------------------------- prep: W transpose->bf16, zero gcnt/ovf
__global__ void prep_all(const float* __restrict__ W1, const float* __restrict__ W2,
                         unsigned short* __restrict__ Wt1, unsigned short* __restrict__ Wt2,
                         int* __restrict__ gcnt, int* __restrict__ ovf) {
    const int idx = blockIdx.x * blockDim.x + threadIdx.x;
    if (idx < 32768) {
        const float* src = (idx < 16384) ? W1 : W2;
        unsigned short* dst = (idx < 16384) ? Wt1 : Wt2;
        const int r = idx & 16383;
        const int n = r & 127, k = r >> 7;
        dst[n * 128 + k] = f2bf(src[k * 128 + n]);
    } else {
        const int z = idx - 32768;
        if (z < BINS) gcnt[z] = 0;
        else if (z == BINS) ovf[0] = 0;
    }
}

// ---------------------------------------------------------------- pass 1: LDS-binned scatter -> dense global bin segments
// packed edge: (ln<<17)|s  (ln = d%NPB < 512, s < 2^17)
__global__ __launch_bounds__(256) void bin_scatter(const int* __restrict__ srcIdx,
                                                   const int* __restrict__ dstIdx,
                                                   int* __restrict__ gcnt,
                                                   int* __restrict__ gbin,
                                                   int* __restrict__ ovf) {
    __shared__ int lsbin[BINS * CAP1];    // 32 KB
    __shared__ int lcnt[BINS];
    __shared__ int lbase[BINS];
    __shared__ int pref[BINS + 1];

    const int tid = threadIdx.x;
    for (int i = tid; i < BINS; i += 256) lcnt[i] = 0;
    __syncthreads();

    const int e0 = blockIdx.x * CHUNK;
    for (int i = tid; i < CHUNK; i += 256) {
        const int e = e0 + i;
        if (e < EDGES) {
            const int d = dstIdx[e];
            const int s = srcIdx[e];
            const int b = d / NPB;
            const int ln = d - b * NPB;
            const int pos = atomicAdd(&lcnt[b], 1);
            if (pos < CAP1) {
                lsbin[b * CAP1 + pos] = (ln << 17) | s;
            } else {
                const int k = atomicAdd(&ovf[0], 1);
                if (k < OVF_CAP) { ovf[1 + 2 * k] = d; ovf[2 + 2 * k] = s; }
            }
        }
    }
    __syncthreads();

    // clamp, reserve global segment space (one atomic per bin per block)
    if (tid < BINS) {
        const int c = min(lcnt[tid], CAP1);
        lcnt[tid] = c;
        lbase[tid] = atomicAdd(&gcnt[tid], c);
    }
    __syncthreads();
    if (tid == 0) {
        int acc = 0;
        for (int b = 0; b < BINS; ++b) { pref[b] = acc; acc += lcnt[b]; }
        pref[BINS] = acc;
    }
    __syncthreads();

    // dense coalesced copy-out: flat index -> (bin, j) via binary search on prefix
    const int total = pref[BINS];
    for (int f = tid; f < total; f += 256) {
        int lo = 0, hi = BINS - 1;
        while (lo < hi) { const int mid = (lo + hi + 1) >> 1; if (pref[mid] <= f) lo = mid; else hi = mid - 1; }
        const int j = f - pref[lo];
        const int gi = lbase[lo] + j;
        const int v = lsbin[lo * CAP1 + j];
        if (gi < GCAP) {
            gbin[(size_t)lo * GCAP + gi] = v;
        } else {
            const int k = atomicAdd(&ovf[0], 1);
            if (k < OVF_CAP) { ovf[1 + 2 * k] = lo * NPB + (v >> 17); ovf[2 + 2 * k] = v & 0x1FFFF; }
        }
    }
}

// ---------------------------------------------------------------- pass 2: per-bin LDS build -> dense cursor/slots
__global__ __launch_bounds__(256) void bin_build(const int* __restrict__ gcnt,
                                                 const int* __restrict__ gbin,
                                                 int* __restrict__ cursor,
                                                 int* __restrict__ slots,
                                                 int* __restrict__ ovf) {
    __shared__ int lcur[NPB];             // 2 KB
    __shared__ int lslot[NPB * SLOT];     // 48 KB
    const int b = blockIdx.x;
    const int tid = threadIdx.x;
    for (int i = tid; i < NPB; i += 256) lcur[i] = 0;
    __syncthreads();

    const int cnt = min(gcnt[b], GCAP);
    for (int i = tid; i < cnt; i += 256) {
        const int v = gbin[(size_t)b * GCAP + i];
        const int ln = v >> 17;
        const int s = v & 0x1FFFF;
        const int pos = atomicAdd(&lcur[ln], 1);
        if (pos < SLOT) {
            lslot[ln * SLOT + pos] = s;
        } else {
            const int k = atomicAdd(&ovf[0], 1);
            if (k < OVF_CAP) { ovf[1 + 2 * k] = b * NPB + ln; ovf[2 + 2 * k] = s; }
        }
    }
    __syncthreads();

    for (int i = tid; i < NPB; i += 256) cursor[b * NPB + i] = lcur[i];
    for (int i = tid; i < NPB * SLOT; i += 256)
        slots[(size_t)b * NPB * SLOT + i] = lslot[i];   // == slots[node*SLOT + j], dense
}

// ---------------------------------------------------------------- GEMM: Y = A @ Wt^T (bf16 out)
template <int A_F32>
__global__ __launch_bounds__(256) void gemm_mfma(const void* __restrict__ Ap,
                                                 const uint4* __restrict__ Wt4,
                                                 unsigned short* __restrict__ outh) {
    __shared__ __align__(16) unsigned char wlds[32768];
    __shared__ __align__(16) unsigned char epi[16384];

    const int tid = threadIdx.x;
    #pragma unroll
    for (int i = 0; i < 8; ++i) {
        const int c = i * 256 + tid;
        const uint4 v = Wt4[c];
        const int byte = (c * 16) ^ (((c >> 4) & 7) << 4);
        *(uint4*)(wlds + byte) = v;
    }

    const int wv = tid >> 6;
    const int l  = tid & 63;
    const int lr = l & 15;
    const int g  = l >> 4;
    const int row0 = blockIdx.x * 64 + wv * 16;

    int arow = row0 + lr;
    if (arow >= NODES) arow = 0;      // clamp (stores guarded)

    bf16x8 af[4];
    if constexpr (A_F32) {
        const float* Af = (const float*)Ap + (size_t)arow * DF + g * 8;
        #pragma unroll
        for (int t = 0; t < 4; ++t) {
            const float4 f0 = *(const float4*)(Af + t * 32);
            const float4 f1 = *(const float4*)(Af + t * 32 + 4);
            bf16x8 v;
            v[0] = (short)f2bf(f0.x); v[1] = (short)f2bf(f0.y);
            v[2] = (short)f2bf(f0.z); v[3] = (short)f2bf(f0.w);
            v[4] = (short)f2bf(f1.x); v[5] = (short)f2bf(f1.y);
            v[6] = (short)f2bf(f1.z); v[7] = (short)f2bf(f1.w);
            af[t] = v;
        }
    } else {
        const unsigned short* Ab = (const unsigned short*)Ap + (size_t)arow * DF + g * 8;
        #pragma unroll
        for (int t = 0; t < 4; ++t) af[t] = *(const bf16x8*)(Ab + t * 32);
    }

    f32x4 acc[8];
    #pragma unroll
    for (int nt = 0; nt < 8; ++nt) acc[nt] = (f32x4)(0.f);

    __syncthreads();

    #pragma unroll
    for (int t = 0; t < 4; ++t) {
        #pragma unroll
        for (int nt = 0; nt < 8; ++nt) {
            const int byte = ((nt * 16 + lr) * 256 + ((((t * 4 + g) * 16) ^ ((l & 7) << 4))));
            const bf16x8 bf = *(const bf16x8*)(wlds + byte);
            acc[nt] = __builtin_amdgcn_mfma_f32_16x16x32_bf16(af[t], bf, acc[nt], 0, 0, 0);
        }
    }

    // epilogue: transpose via per-wave LDS for coalesced bf16 row stores
    unsigned char* my = epi + wv * 4096;
    #pragma unroll
    for (int nt = 0; nt < 8; ++nt) {
        #pragma unroll
        for (int r = 0; r < 4; ++r) {
            const int R = g * 4 + r;
            const int byte = (R * 256 + (nt * 16 + lr) * 2) ^ ((R & 7) << 4);
            *(unsigned short*)(my + byte) = f2bf(acc[nt][r]);
        }
    }
    __syncthreads();
    #pragma unroll
    for (int p = 0; p < 4; ++p) {
        const int R = p * 4 + g;
        const uint4 v = *(const uint4*)(my + ((R * 256 + lr * 16) ^ ((R & 7) << 4)));
        const int gr = row0 + R;
        if (gr < NODES) *(uint4*)(outh + (size_t)gr * DF + lr * 8) = v;
    }
}

// ---------------------------------------------------------------- gather+bias(+relu): out[i] = y[i] + sum_N y[j] + b
template <int RELU, int OUT_F32>
__global__ __launch_bounds__(256) void gather_bias(const uint4* __restrict__ yb,
                                                   const int* __restrict__ cursor,
                                                   const int* __restrict__ slots,
                                                   const int* __restrict__ ovf,
                                                   const float* __restrict__ bias,
                                                   void* __restrict__ outp) {
    const int gid = blockIdx.x * 256 + threadIdx.x;
    const int node = gid >> 4;
    const int lane = gid & 15;
    if (node >= NODES) return;

    float a[8];
    {
        const uint4 u = yb[(size_t)node * 16 + lane];
        a[0] = bflo(u.x); a[1] = bfhi(u.x);
        a[2] = bflo(u.y); a[3] = bfhi(u.y);
        a[4] = bflo(u.z); a[5] = bfhi(u.z);
        a[6] = bflo(u.w); a[7] = bfhi(u.w);
    }
    const int deg = min(cursor[node], SLOT);
    const int base = node * SLOT;
    int j = 0;
    for (; j + 4 <= deg; j += 4) {
        const int s0 = slots[base + j + 0];
        const int s1 = slots[base + j + 1];
        const int s2 = slots[base + j + 2];
        const int s3 = slots[base + j + 3];
        const uint4 v0 = yb[(size_t)s0 * 16 + lane];
        const uint4 v1 = yb[(size_t)s1 * 16 + lane];
        const uint4 v2 = yb[(size_t)s2 * 16 + lane];
        const uint4 v3 = yb[(size_t)s3 * 16 + lane];
        a[0] += bflo(v0.x); a[1] += bfhi(v0.x); a[2] += bflo(v0.y); a[3] += bfhi(v0.y);
        a[4] += bflo(v0.z); a[5] += bfhi(v0.z); a[6] += bflo(v0.w); a[7] += bfhi(v0.w);
        a[0] += bflo(v1.x); a[1] += bfhi(v1.x); a[2] += bflo(v1.y); a[3] += bfhi(v1.y);
        a[4] += bflo(v1.z); a[5] += bfhi(v1.z); a[6] += bflo(v1.w); a[7] += bfhi(v1.w);
        a[0] += bflo(v2.x); a[1] += bfhi(v2.x); a[2] += bflo(v2.y); a[3] += bfhi(v2.y);
        a[4] += bflo(v2.z); a[5] += bfhi(v2.z); a[6] += bflo(v2.w); a[7] += bfhi(v2.w);
        a[0] += bflo(v3.x); a[1] += bfhi(v3.x); a[2] += bflo(v3.y); a[3] += bfhi(v3.y);
        a[4] += bflo(v3.z); a[5] += bfhi(v3.z); a[6] += bflo(v3.w); a[7] += bfhi(v3.w);
    }
    for (; j < deg; ++j) {
        const uint4 v = yb[(size_t)slots[base + j] * 16 + lane];
        a[0] += bflo(v.x); a[1] += bfhi(v.x); a[2] += bflo(v.y); a[3] += bfhi(v.y);
        a[4] += bflo(v.z); a[5] += bfhi(v.z); a[6] += bflo(v.w); a[7] += bfhi(v.w);
    }

    // overflow edges (count 0 on this input; one cached uniform read)
    const int oc = ovf[0];
    if (oc > 0) {
        const int m = min(oc, OVF_CAP);
        for (int k = 0; k < m; ++k) {
            if (ovf[1 + 2 * k] == node) {
                const uint4 v = yb[(size_t)ovf[2 + 2 * k] * 16 + lane];
                a[0] += bflo(v.x); a[1] += bfhi(v.x); a[2] += bflo(v.y); a[3] += bfhi(v.y);
                a[4] += bflo(v.z); a[5] += bfhi(v.z); a[6] += bflo(v.w); a[7] += bfhi(v.w);
            }
        }
    }

    const float4 bb0 = ((const float4*)bias)[lane * 2 + 0];
    const float4 bb1 = ((const float4*)bias)[lane * 2 + 1];
    a[0] += bb0.x; a[1] += bb0.y; a[2] += bb0.z; a[3] += bb0.w;
    a[4] += bb1.x; a[5] += bb1.y; a[6] += bb1.z; a[7] += bb1.w;
    if (RELU) {
        #pragma unroll
        for (int e = 0; e < 8; ++e) a[e] = fmaxf(a[e], 0.f);
    }

    if constexpr (OUT_F32) {
        float* of = (float*)outp + (size_t)node * DF + lane * 8;
        *(float4*)(of + 0) = make_float4(a[0], a[1], a[2], a[3]);
        *(float4*)(of + 4) = make_float4(a[4], a[5], a[6], a[7]);
    } else {
        uint4 o;
        o.x = (unsigned)f2bf(a[0]) | ((unsigned)f2bf(a[1]) << 16);
        o.y = (unsigned)f2bf(a[2]) | ((unsigned)f2bf(a[3]) << 16);
        o.z = (unsigned)f2bf(a[4]) | ((unsigned)f2bf(a[5]) << 16);
        o.w = (unsigned)f2bf(a[6]) | ((unsigned)f2bf(a[7]) << 16);
        ((uint4*)outp)[(size_t)node * 16 + lane] = o;
    }
}

extern "C" void kernel_launch(void* const* d_in, const int* in_sizes, int n_in,
                              void* d_out, int out_size, void* d_ws, size_t ws_size,
                              hipStream_t stream) {
    const float* x  = (const float*)d_in[0];
    const int*   ei = (const int*)d_in[1];
    const float* W1 = (const float*)d_in[2];
    const float* b1 = (const float*)d_in[3];
    const float* W2 = (const float*)d_in[4];
    const float* b2 = (const float*)d_in[5];
    float* out = (float*)d_out;

    const int* src = ei;
    const int* dst = ei + EDGES;

    // workspace layout
    unsigned short* B0  = (unsigned short*)d_ws;                  // NODES*DF bf16 (y / z)
    unsigned short* B1  = B0 + (size_t)NODES * DF;                // NODES*DF bf16 (h)
    unsigned short* Wt1 = B1 + (size_t)NODES * DF;                // 16384
    unsigned short* Wt2 = Wt1 + 16384;                            // 16384
    int* cursor = (int*)(Wt2 + 16384);                            // NODES (fully written by bin_build)
    int* slots  = cursor + NODES;                                 // NODES*SLOT (9.6 MB)
    int* gcnt   = slots + (size_t)NODES * SLOT;                   // BINS
    int* ovf    = gcnt + BINS;                                    // 1 + 2*OVF_CAP
    int* gbin   = ovf + 1 + 2 * OVF_CAP;                          // BINS*GCAP ints (3.2 MB)

    // 1: W transpose + zero gcnt/ovf
    prep_all<<<(32768 + BINS + 1 + 255) / 256, 256, 0, stream>>>(W1, W2, Wt1, Wt2, gcnt, ovf);
    // 2: pass 1 — LDS-binned scatter to dense bin segments (packed ints)
    bin_scatter<<<P1BLK, 256, 0, stream>>>(src, dst, gcnt, gbin, ovf);
    // 3: pass 2 — per-bin LDS build -> dense cursor/slots
    bin_build<<<BINS, 256, 0, stream>>>(gcnt, gbin, cursor, slots, ovf);

    const int gblocks = (NODES * 16 + 255) / 256;   // 6250

    // 4: y = x @ W1
    gemm_mfma<1><<<MBLK, 256, 0, stream>>>((const void*)x, (const uint4*)Wt1, B0);
    // 5: h = relu(y_i + sum_N y_j + b1)
    gather_bias<1, 0><<<gblocks, 256, 0, stream>>>((const uint4*)B0, cursor, slots, ovf, b1, B1);
    // 6: z = h @ W2
    gemm_mfma<0><<<MBLK, 256, 0, stream>>>((const void*)B1, (const uint4*)Wt2, B0);
    // 7: out = z_i + sum_N z_j + b2
    gather_bias<0, 1><<<gblocks, 256, 0, stream>>>((const uint4*)B0, cursor, slots, ovf, b2, out);
}